// Round 11
// baseline (379.846 us; speedup 1.0000x reference)
//
#include <hip/hip_runtime.h>
#include <hip/hip_bf16.h>

#define B_ 4
#define C_ 512
#define L_ 2048
#define H_ 8
#define E_ 64
// sqrt(0.125 * log2(e)) — folded into Q (and K=Q) so QK^T yields log2-domain scores
#define QSCALE 0.4246609f
#define NUNITS 2048

typedef __attribute__((ext_vector_type(8))) short bf16x8;
typedef __attribute__((ext_vector_type(4))) float f32x4;
typedef __attribute__((ext_vector_type(4))) unsigned short u16x4;

static __device__ __forceinline__ unsigned short f2bf(float f) {
    union { float f; unsigned u; } v; v.f = f;
    unsigned r = v.u + 0x7FFFu + ((v.u >> 16) & 1u);
    return (unsigned short)(r >> 16);
}

// light barrier: make LDS writes visible, do NOT drain vmcnt (loads stay in flight)
#define LBAR() do { asm volatile("s_waitcnt lgkmcnt(0)" ::: "memory"); \
                    __builtin_amdgcn_s_barrier(); } while (0)

// ---------------- Pass A: cast x -> xb (bf16, [b][c][l]) and xt (bf16, [b][l][c]) ----------------
__global__ __launch_bounds__(256) void prep_kernel(const float* __restrict__ x,
                                                   unsigned short* __restrict__ xb,
                                                   unsigned short* __restrict__ xt) {
    const int lt = blockIdx.x, ct = blockIdx.y, b = blockIdx.z;
    const int l0 = lt * 64, c0 = ct * 64;
    const int t = threadIdx.x;
    __shared__ unsigned short T[64 * 72];

    const int cl = t >> 2, lo = (t & 3) * 16;
    const float* src = x + ((size_t)(b * C_ + c0 + cl)) * L_ + l0 + lo;
    unsigned short u[16];
    #pragma unroll
    for (int j = 0; j < 16; j += 4) {
        float4 v = *reinterpret_cast<const float4*>(src + j);
        u[j] = f2bf(v.x); u[j + 1] = f2bf(v.y); u[j + 2] = f2bf(v.z); u[j + 3] = f2bf(v.w);
    }
    unsigned short* xbp = xb + ((size_t)(b * C_ + c0 + cl)) * L_ + l0 + lo;
    reinterpret_cast<uint4*>(xbp)[0] = reinterpret_cast<uint4*>(u)[0];
    reinterpret_cast<uint4*>(xbp)[1] = reinterpret_cast<uint4*>(u)[1];
    reinterpret_cast<uint4*>(&T[cl * 72 + lo])[0] = reinterpret_cast<uint4*>(u)[0];
    reinterpret_cast<uint4*>(&T[cl * 72 + lo + 8])[0] = reinterpret_cast<uint4*>(u)[1];
    __syncthreads();
    const int ll = t >> 2, co = (t & 3) * 16;
    unsigned short v16[16];
    #pragma unroll
    for (int j = 0; j < 16; ++j) v16[j] = T[(co + j) * 72 + ll];
    unsigned short* xtp = xt + ((size_t)b * L_ + l0 + ll) * C_ + c0 + co;
    reinterpret_cast<uint4*>(xtp)[0] = reinterpret_cast<uint4*>(v16)[0];
    reinterpret_cast<uint4*>(xtp)[1] = reinterpret_cast<uint4*>(v16)[1];
}

// ---------------- Pass A2: cast W fp32 -> bf16 ----------------
__global__ __launch_bounds__(256) void wcast_kernel(const float* __restrict__ W,
                                                    unsigned short* __restrict__ Wb) {
    const int i = blockIdx.x * 256 + threadIdx.x;
    float4 v = reinterpret_cast<const float4*>(W)[i];
    union { unsigned short u[4]; unsigned long long ll; } o;
    o.u[0] = f2bf(v.x); o.u[1] = f2bf(v.y); o.u[2] = f2bf(v.z); o.u[3] = f2bf(v.w);
    reinterpret_cast<unsigned long long*>(Wb)[i] = o.ll;
}

// ---------------- Pass B: Q = (W x + b) * QSCALE, bf16 [(b*H+h)][l][e] ----------------
__global__ __launch_bounds__(256) void proj_kernel(const unsigned short* __restrict__ Wb,
                                                   const float* __restrict__ bq,
                                                   const unsigned short* __restrict__ xt,
                                                   unsigned short* __restrict__ qb) {
    const int lt = blockIdx.x, h = blockIdx.y, b = blockIdx.z;
    const int tid = threadIdx.x, w = tid >> 6, lane = tid & 63;
    const int lr = lane & 15, lg = lane >> 4;
    const int l = lt * 64 + w * 16 + lr;
    const int o0 = h * 64;

    f32x4 acc[4] = {};
    const unsigned short* xrow = xt + ((size_t)b * L_ + l) * C_;
    for (int ks = 0; ks < 16; ++ks) {
        bf16x8 bf = *reinterpret_cast<const bf16x8*>(xrow + ks * 32 + lg * 8);
        #pragma unroll
        for (int mt = 0; mt < 4; ++mt) {
            bf16x8 af = *reinterpret_cast<const bf16x8*>(Wb + (size_t)(o0 + mt * 16 + lr) * C_ + ks * 32 + lg * 8);
            acc[mt] = __builtin_amdgcn_mfma_f32_16x16x32_bf16(af, bf, acc[mt], 0, 0, 0);
        }
    }
    const int bh = b * H_ + h;
    unsigned short* qrow = qb + ((size_t)bh * L_ + l) * 64;
    #pragma unroll
    for (int mt = 0; mt < 4; ++mt) {
        const int e0 = mt * 16 + lg * 4;
        const float4 bb = *reinterpret_cast<const float4*>(bq + o0 + e0);
        union { unsigned short u[4]; unsigned long long ll; } o;
        o.u[0] = f2bf((acc[mt][0] + bb.x) * QSCALE);
        o.u[1] = f2bf((acc[mt][1] + bb.y) * QSCALE);
        o.u[2] = f2bf((acc[mt][2] + bb.z) * QSCALE);
        o.u[3] = f2bf((acc[mt][3] + bb.w) * QSCALE);
        *reinterpret_cast<unsigned long long*>(qrow + e0) = o.ll;
    }
}

// ---------------- Pass C: fused attention, 4 waves/block, 64q x 256c per block ----------------
// PV step s: 4 pa reads (LDS, swizzled) + 4 V frag loads (global) + 16 MFMAs
#define PV_STEP(S)                                                                        \
    {                                                                                     \
        bf16x8 vf[4];                                                                     \
        _Pragma("unroll")                                                                 \
        for (int ct = 0; ct < 4; ++ct)                                                    \
            vf[ct] = *reinterpret_cast<const bf16x8*>(                                    \
                Vbase + (size_t)(c0w + ct * 16 + lr) * L_ + k0 + (S) * 32 + lg * 8);      \
        bf16x8 pa[4];                                                                     \
        _Pragma("unroll")                                                                 \
        for (int qs = 0; qs < 4; ++qs) {                                                  \
            const int row = qs * 16 + lr;                                                 \
            const int g2 = ((S) * 4 + lg) ^ (lr & 7);                                     \
            pa[qs] = *reinterpret_cast<const bf16x8*>(&P[row * 128 + (g2 << 3)]);         \
        }                                                                                 \
        __builtin_amdgcn_s_setprio(1);                                                    \
        _Pragma("unroll")                                                                 \
        for (int qs = 0; qs < 4; ++qs)                                                    \
            _Pragma("unroll")                                                             \
            for (int ct = 0; ct < 4; ++ct)                                                \
                acc[qs][ct] = __builtin_amdgcn_mfma_f32_16x16x32_bf16(                    \
                    pa[qs], vf[ct], acc[qs][ct], 0, 0, 0);                                \
        __builtin_amdgcn_s_setprio(0);                                                    \
    }

__global__ __launch_bounds__(256, 4) void pv_kernel(const unsigned short* __restrict__ qb,
                                                    const unsigned short* __restrict__ xb,
                                                    float* __restrict__ out,
                                                    int* __restrict__ counter) {
    const int tid = threadIdx.x, w = tid >> 6, lane = tid & 63;
    const int lr = lane & 15, lg = lane >> 4;

    __shared__ unsigned short Qt[64 * 64];   // swizzled Q tile (8 KB)
    __shared__ unsigned short P[64 * 128];   // 64q x 128k bf16, XOR-swizzled (16 KB)
    __shared__ float rsT[64][4];             // [q][wave] rowsum partials (1 KB)
    __shared__ int s_u;

    for (;;) {
        __syncthreads();   // previous unit's readers of Qt/P/rsT/s_u are done
        if (tid == 0) s_u = atomicAdd(counter, 1);
        __syncthreads();
        const int u = s_u;
        if (u >= NUNITS) return;

        // heavy q-tiles first (LPT packing on the dynamic queue)
        const int qt = 31 - (u >> 6);
        const int rr = u & 63;
        const int bh = rr >> 1, ch = rr & 1;
        const int b = bh >> 3;
        const int q0 = qt * 64, qlim = q0 + 63;
        const int nkt = (q0 >> 7) + 1;
        const int c0w = ch * 256 + w * 64;        // this wave's 64-channel slice
        const unsigned short* Qbase = qb + (size_t)bh * L_ * 64;
        const unsigned short* Vbase = xb + (size_t)b * C_ * L_;

        // stage Q tile (64 rows x 64 e) into LDS, granule g -> g ^ (row&7)
        {
            const int r = tid >> 2, seg = tid & 3;
            const unsigned short* src = Qbase + (size_t)(q0 + r) * 64 + seg * 16;
            bf16x8 v0 = *reinterpret_cast<const bf16x8*>(src);
            bf16x8 v1 = *reinterpret_cast<const bf16x8*>(src + 8);
            const int g0 = seg * 2, g1 = seg * 2 + 1;
            *reinterpret_cast<bf16x8*>(&Qt[r * 64 + ((g0 ^ (r & 7)) << 3)]) = v0;
            *reinterpret_cast<bf16x8*>(&Qt[r * 64 + ((g1 ^ (r & 7)) << 3)]) = v1;
        }

        f32x4 acc[4][4] = {};                     // [qsub][ct]
        float rs[4] = {0.f, 0.f, 0.f, 0.f};       // per qsub, lane partial

        LBAR();   // Qt visible

        #pragma unroll 1
        for (int kt = 0; kt < nkt; ++kt) {
            const int k0 = kt * 128;
            const int ksmax = min(4, ((qlim - k0) >> 5) + 1);   // 2 or 4
            const bool active = (w < ksmax);                     // wave's 32k slice live?
            const int kw0 = k0 + w * 32;

            if (active) {
                // K A-frags for this wave's 32k (2 ksub x 2 e-halves), direct from global
                bf16x8 kb[2][2];
                #pragma unroll
                for (int ksub = 0; ksub < 2; ++ksub) {
                    const size_t krow = (size_t)(kw0 + ksub * 16 + lr) * 64;
                    kb[ksub][0] = *reinterpret_cast<const bf16x8*>(Qbase + krow + lg * 8);
                    kb[ksub][1] = *reinterpret_cast<const bf16x8*>(Qbase + krow + 32 + lg * 8);
                }
                #pragma unroll
                for (int qs = 0; qs < 4; ++qs) {
                    // Q B-frags from swizzled Qt
                    const int qrow = qs * 16 + lr;
                    bf16x8 qf0 = *reinterpret_cast<const bf16x8*>(&Qt[qrow * 64 + ((lg ^ (qrow & 7)) << 3)]);
                    bf16x8 qf1 = *reinterpret_cast<const bf16x8*>(&Qt[qrow * 64 + (((4 + lg) ^ (qrow & 7)) << 3)]);
                    const int q = q0 + qrow;
                    #pragma unroll
                    for (int ksub = 0; ksub < 2; ++ksub) {
                        f32x4 z = {};
                        z = __builtin_amdgcn_mfma_f32_16x16x32_bf16(kb[ksub][0], qf0, z, 0, 0, 0);
                        z = __builtin_amdgcn_mfma_f32_16x16x32_bf16(kb[ksub][1], qf1, z, 0, 0, 0);
                        const int kbase = kw0 + ksub * 16 + lg * 4;
                        const float p0 = (kbase + 0 <= q) ? exp2f(z[0]) : 0.f;
                        const float p1 = (kbase + 1 <= q) ? exp2f(z[1]) : 0.f;
                        const float p2 = (kbase + 2 <= q) ? exp2f(z[2]) : 0.f;
                        const float p3 = (kbase + 3 <= q) ? exp2f(z[3]) : 0.f;
                        rs[qs] += (p0 + p1) + (p2 + p3);
                        unsigned r01, r23;
                        asm("v_cvt_pk_bf16_f32 %0, %1, %2" : "=v"(r01) : "v"(p0), "v"(p1));
                        asm("v_cvt_pk_bf16_f32 %0, %1, %2" : "=v"(r23) : "v"(p2), "v"(p3));
                        // P[qrow][kl], kl = w*32 + ksub*16 + lg*4; granule swizzle ^ (qrow&7)
                        const int kl = w * 32 + ksub * 16 + lg * 4;
                        const int g = (kl >> 3) ^ (qrow & 7);
                        const unsigned long long pk = ((unsigned long long)r23 << 32) | r01;
                        *reinterpret_cast<unsigned long long*>(&P[qrow * 128 + (g << 3) + (kl & 7)]) = pk;
                    }
                }
            }
            LBAR();   // P visible; global loads stay in flight

            // PV: wave owns 64 channels; steps limited to written P region
            PV_STEP(0)
            PV_STEP(1)
            if (ksmax == 4) {
                PV_STEP(2)
                PV_STEP(3)
            }
            LBAR();   // P WAR protection before next S overwrite
        }

        // rowsum: reduce over lg within wave, then merge the 4 k-slice waves via LDS
        #pragma unroll
        for (int qs = 0; qs < 4; ++qs) {
            float t0 = __shfl_xor(rs[qs], 16); rs[qs] += t0;
            float t1 = __shfl_xor(rs[qs], 32); rs[qs] += t1;
        }
        if (lg == 0) {
            #pragma unroll
            for (int qs = 0; qs < 4; ++qs) rsT[qs * 16 + lr][w] = rs[qs];
        }
        LBAR();

        // epilogue: li per q, bf16 residual, NT streaming stores
        const unsigned short* xres = xb + (size_t)b * C_ * L_;
        float* ob = out + (size_t)bh * C_ * L_;
        #pragma unroll
        for (int qs = 0; qs < 4; ++qs) {
            f32x4 li;
            #pragma unroll
            for (int r = 0; r < 4; ++r) {
                const f32x4 s4 = *reinterpret_cast<const f32x4*>(&rsT[qs * 16 + lg * 4 + r][0]);
                li[r] = 1.f / ((s4[0] + s4[1]) + (s4[2] + s4[3]));
            }
            const int lbase = q0 + qs * 16 + lg * 4;
            #pragma unroll
            for (int ct = 0; ct < 4; ++ct) {
                const int c = c0w + ct * 16 + lr;
                const u16x4 rv = __builtin_nontemporal_load(
                    reinterpret_cast<const u16x4*>(xres + (size_t)c * L_ + lbase));
                f32x4 o;
                o[0] = acc[qs][ct][0] * li[0] + __uint_as_float((unsigned)rv[0] << 16);
                o[1] = acc[qs][ct][1] * li[1] + __uint_as_float((unsigned)rv[1] << 16);
                o[2] = acc[qs][ct][2] * li[2] + __uint_as_float((unsigned)rv[2] << 16);
                o[3] = acc[qs][ct][3] * li[3] + __uint_as_float((unsigned)rv[3] << 16);
                __builtin_nontemporal_store(o, reinterpret_cast<f32x4*>(ob + (size_t)c * L_ + lbase));
            }
        }
    }
}

extern "C" void kernel_launch(void* const* d_in, const int* in_sizes, int n_in,
                              void* d_out, int out_size, void* d_ws, size_t ws_size,
                              hipStream_t stream) {
    const float* x  = (const float*)d_in[0];
    const float* Wq = (const float*)d_in[1];
    const float* bq = (const float*)d_in[2];
    float* out = (float*)d_out;

    unsigned short* xb   = (unsigned short*)d_ws;                        // B*C*L bf16   = 8 MiB
    unsigned short* xt   = xb + (size_t)B_ * C_ * L_;                    // B*L*C bf16   = 8 MiB
    unsigned short* qbuf = xt + (size_t)B_ * L_ * C_;                    // B*H*L*E bf16 = 8 MiB
    unsigned short* Wb   = qbuf + (size_t)B_ * H_ * L_ * E_;             // 512 KiB
    int* counter = (int*)(Wb + (size_t)H_ * E_ * C_);                    // 4 B

    (void)hipMemsetAsync(counter, 0, 4, stream);
    prep_kernel<<<dim3(32, 8, 4), 256, 0, stream>>>(x, xb, xt);
    wcast_kernel<<<dim3(256), 256, 0, stream>>>(Wq, Wb);
    proj_kernel<<<dim3(32, 8, 4), 256, 0, stream>>>(Wb, bq, xt, qbuf);
    pv_kernel<<<dim3(1024), 256, 0, stream>>>(qbuf, xb, out, counter);
}